// Round 1
// baseline (686.037 us; speedup 1.0000x reference)
//
#include <hip/hip_runtime.h>
#include <hip/hip_bf16.h>

#define TT 8192
#define DD 2048
#define HH 1408
#define EE 8
#define KTOP 2
#define NA (TT * KTOP)  // 16384 assignments

typedef __attribute__((ext_vector_type(8))) short bh8;   // 8 bf16 = 4 VGPR
typedef __attribute__((ext_vector_type(4))) float f4;    // MFMA accumulator

typedef __attribute__((address_space(1))) const void gconst_t;
typedef __attribute__((address_space(3))) void lds_t;

__device__ __forceinline__ void glds16(const void* g, void* l) {
  __builtin_amdgcn_global_load_lds((gconst_t*)g, (lds_t*)l, 16, 0, 0);
}

__device__ __forceinline__ float silu_f(float x) { return x / (1.f + __expf(-x)); }

// ---------------- bookkeeping kernels ----------------
__global__ void k_init(int* counts) {
  int i = threadIdx.x;
  if (i < EE) counts[i] = 0;
}

__global__ void k_count(const int* __restrict__ idx, int* __restrict__ counts) {
  int i = blockIdx.x * 256 + threadIdx.x;
  if (i < NA) atomicAdd(&counts[idx[i]], 1);
}

__global__ void k_scan(const int* __restrict__ counts, int* __restrict__ off,
                       int* __restrict__ cursor) {
  if (threadIdx.x == 0) {
    int a = 0;
    for (int e = 0; e < EE; ++e) { off[e] = a; cursor[e] = a; a += counts[e]; }
    off[EE] = a;
  }
}

__global__ void k_scatter(const int* __restrict__ idx, const float* __restrict__ sc,
                          int* __restrict__ cursor, int* __restrict__ rows_token,
                          float* __restrict__ rows_score) {
  int i = blockIdx.x * 256 + threadIdx.x;
  if (i < NA) {
    int e = idx[i];
    int p = atomicAdd(&cursor[e], 1);
    rows_token[p] = i / KTOP;
    rows_score[p] = sc[i];
  }
}

// ---------------- conversion kernels ----------------
__global__ void k_cvtx(const float* __restrict__ src, __hip_bfloat16* __restrict__ dst) {
  int i = blockIdx.x * 256 + threadIdx.x;  // indexes float4
  const int n4 = TT * DD / 4;
  if (i < n4) {
    float4 v = reinterpret_cast<const float4*>(src)[i];
    union { ushort4 u; __hip_bfloat16 h[4]; } o;
    o.h[0] = __float2bfloat16(v.x); o.h[1] = __float2bfloat16(v.y);
    o.h[2] = __float2bfloat16(v.z); o.h[3] = __float2bfloat16(v.w);
    reinterpret_cast<ushort4*>(dst)[i] = o.u;
  }
}

// transpose+convert: src fp32 [B][R][C] -> dst bf16 [B][C][R]
__global__ void k_tc(const float* __restrict__ src, __hip_bfloat16* __restrict__ dst,
                     int R, int C) {
  __shared__ float t[32][33];
  const float* s = src + (size_t)blockIdx.z * R * C;
  __hip_bfloat16* d = dst + (size_t)blockIdx.z * R * C;
  int c0 = blockIdx.x * 32, r0 = blockIdx.y * 32;
  int x = threadIdx.x;
  for (int j = threadIdx.y; j < 32; j += 8)
    t[j][x] = s[(size_t)(r0 + j) * C + c0 + x];
  __syncthreads();
  for (int j = threadIdx.y; j < 32; j += 8)
    d[(size_t)(c0 + j) * R + r0 + x] = __float2bfloat16(t[x][j]);
}

// ---------------- GEMM1: h = silu(Xe*Wg) * (Xe*Wu) ----------------
// A: gathered rows of xb [ne][DD]; B: Wgb/Wub transposed [E][HH][DD] (n-major, k-contig)
// tile: 128 rows x (64 gate + 64 up cols), BK=64, 4 waves (each 32 rows x 128 cols)
__global__ __launch_bounds__(256, 2) void k_gemm1(
    const __hip_bfloat16* __restrict__ xb,
    const __hip_bfloat16* __restrict__ Wgb,
    const __hip_bfloat16* __restrict__ Wub,
    const int* __restrict__ rows_token,
    const int* __restrict__ off,
    __hip_bfloat16* __restrict__ hbuf) {
  const int e = blockIdx.z;
  const int oe = off[e];
  const int ne = off[e + 1] - oe;
  if (ne <= 0) return;
  const int n0 = blockIdx.x * 64;
  const int tid = threadIdx.x;
  const int lane = tid & 63;
  const int w = tid >> 6;

  __shared__ __hip_bfloat16 As[128 * 64];
  __shared__ __hip_bfloat16 Bs[128 * 64];

  // per-lane swizzled chunk offset (bf16 elems): stage source pre-swizzled so
  // linear global_load_lds dest + swizzled ds_read agree (rule #21)
  const int kel = (((lane & 7) ^ (lane >> 3)) << 3);

  const __hip_bfloat16* bsrc[4];
#pragma unroll
  for (int i = 0; i < 4; ++i) {
    int bn = ((w * 4 + i) << 3) + (lane >> 3);
    const __hip_bfloat16* base =
        (bn < 64) ? (Wgb + ((size_t)e * HH + (n0 + bn)) * DD)
                  : (Wub + ((size_t)e * HH + (n0 + bn - 64)) * DD);
    bsrc[i] = base + kel;
  }

  for (int m0 = blockIdx.y * 128; m0 < ne; m0 += gridDim.y * 128) {
    const __hip_bfloat16* asrc[4];
#pragma unroll
    for (int i = 0; i < 4; ++i) {
      int r = ((w * 4 + i) << 3) + (lane >> 3);
      int rr = m0 + r; rr = rr < ne ? rr : ne - 1;
      asrc[i] = xb + (size_t)rows_token[oe + rr] * DD + kel;
    }

    f4 acc[2][8];
#pragma unroll
    for (int mf = 0; mf < 2; ++mf)
#pragma unroll
      for (int nf = 0; nf < 8; ++nf)
        acc[mf][nf] = (f4){0.f, 0.f, 0.f, 0.f};

    for (int k0 = 0; k0 < DD; k0 += 64) {
#pragma unroll
      for (int i = 0; i < 4; ++i) {
        glds16(asrc[i] + k0, As + ((w * 4 + i) << 9));
        glds16(bsrc[i] + k0, Bs + ((w * 4 + i) << 9));
      }
      __syncthreads();
#pragma unroll
      for (int kk = 0; kk < 2; ++kk) {
        const int kByte = (kk * 32 + ((lane >> 4) << 3)) * 2;
        bh8 a[2], b[8];
#pragma unroll
        for (int mf = 0; mf < 2; ++mf) {
          int row = (w << 5) + mf * 16 + (lane & 15);
          int ad = row * 128 + (kByte ^ ((row & 7) << 4));
          a[mf] = *reinterpret_cast<const bh8*>(reinterpret_cast<const char*>(As) + ad);
        }
#pragma unroll
        for (int nf = 0; nf < 8; ++nf) {
          int bn = nf * 16 + (lane & 15);
          int ad = bn * 128 + (kByte ^ ((bn & 7) << 4));
          b[nf] = *reinterpret_cast<const bh8*>(reinterpret_cast<const char*>(Bs) + ad);
        }
#pragma unroll
        for (int mf = 0; mf < 2; ++mf)
#pragma unroll
          for (int nf = 0; nf < 8; ++nf)
            acc[mf][nf] = __builtin_amdgcn_mfma_f32_16x16x32_bf16(a[mf], b[nf], acc[mf][nf], 0, 0, 0);
      }
      __syncthreads();
    }

    // epilogue: silu(gate) * up -> hbuf (gate frag nf pairs with up frag nf+4, same col)
    const int cb = n0 + (lane & 15);
#pragma unroll
    for (int mf = 0; mf < 2; ++mf) {
#pragma unroll
      for (int reg = 0; reg < 4; ++reg) {
        int grow = m0 + (w << 5) + mf * 16 + ((lane >> 4) << 2) + reg;
        if (grow < ne) {
          size_t hb = (size_t)(oe + grow) * HH;
#pragma unroll
          for (int nf = 0; nf < 4; ++nf) {
            float g = acc[mf][nf][reg];
            float u = acc[mf][nf + 4][reg];
            hbuf[hb + cb + nf * 16] = __float2bfloat16(silu_f(g) * u);
          }
        }
      }
    }
  }
}

// ---------------- GEMM2: y[token] += score * (h_e * Wd_e) ----------------
// A: hbuf rows [ne][HH]; B: Wdb transposed [E][DD][HH]; tile 128x128, BK=64
__global__ __launch_bounds__(256, 2) void k_gemm2(
    const __hip_bfloat16* __restrict__ hbuf,
    const __hip_bfloat16* __restrict__ Wdb,
    const int* __restrict__ rows_token,
    const float* __restrict__ rows_score,
    const int* __restrict__ off,
    float* __restrict__ y) {
  const int e = blockIdx.z;
  const int oe = off[e];
  const int ne = off[e + 1] - oe;
  if (ne <= 0) return;
  const int n0 = blockIdx.x * 128;
  const int tid = threadIdx.x;
  const int lane = tid & 63;
  const int w = tid >> 6;

  __shared__ __hip_bfloat16 As[128 * 64];
  __shared__ __hip_bfloat16 Bs[128 * 64];
  const int kel = (((lane & 7) ^ (lane >> 3)) << 3);

  const __hip_bfloat16* bsrc[4];
#pragma unroll
  for (int i = 0; i < 4; ++i) {
    int bn = ((w * 4 + i) << 3) + (lane >> 3);
    bsrc[i] = Wdb + ((size_t)e * DD + (n0 + bn)) * HH + kel;
  }

  for (int m0 = blockIdx.y * 128; m0 < ne; m0 += gridDim.y * 128) {
    const __hip_bfloat16* asrc[4];
#pragma unroll
    for (int i = 0; i < 4; ++i) {
      int r = ((w * 4 + i) << 3) + (lane >> 3);
      int rr = m0 + r; rr = rr < ne ? rr : ne - 1;
      asrc[i] = hbuf + (size_t)(oe + rr) * HH + kel;
    }

    f4 acc[2][8];
#pragma unroll
    for (int mf = 0; mf < 2; ++mf)
#pragma unroll
      for (int nf = 0; nf < 8; ++nf)
        acc[mf][nf] = (f4){0.f, 0.f, 0.f, 0.f};

    for (int k0 = 0; k0 < HH; k0 += 64) {
#pragma unroll
      for (int i = 0; i < 4; ++i) {
        glds16(asrc[i] + k0, As + ((w * 4 + i) << 9));
        glds16(bsrc[i] + k0, Bs + ((w * 4 + i) << 9));
      }
      __syncthreads();
#pragma unroll
      for (int kk = 0; kk < 2; ++kk) {
        const int kByte = (kk * 32 + ((lane >> 4) << 3)) * 2;
        bh8 a[2], b[8];
#pragma unroll
        for (int mf = 0; mf < 2; ++mf) {
          int row = (w << 5) + mf * 16 + (lane & 15);
          int ad = row * 128 + (kByte ^ ((row & 7) << 4));
          a[mf] = *reinterpret_cast<const bh8*>(reinterpret_cast<const char*>(As) + ad);
        }
#pragma unroll
        for (int nf = 0; nf < 8; ++nf) {
          int bn = nf * 16 + (lane & 15);
          int ad = bn * 128 + (kByte ^ ((bn & 7) << 4));
          b[nf] = *reinterpret_cast<const bh8*>(reinterpret_cast<const char*>(Bs) + ad);
        }
#pragma unroll
        for (int mf = 0; mf < 2; ++mf)
#pragma unroll
          for (int nf = 0; nf < 8; ++nf)
            acc[mf][nf] = __builtin_amdgcn_mfma_f32_16x16x32_bf16(a[mf], b[nf], acc[mf][nf], 0, 0, 0);
      }
      __syncthreads();
    }

    // epilogue: scale by gate score, scatter-add into y
#pragma unroll
    for (int mf = 0; mf < 2; ++mf) {
#pragma unroll
      for (int reg = 0; reg < 4; ++reg) {
        int grow = m0 + (w << 5) + mf * 16 + ((lane >> 4) << 2) + reg;
        if (grow < ne) {
          int tok = rows_token[oe + grow];
          float sc = rows_score[oe + grow];
          float* yr = y + (size_t)tok * DD + n0 + (lane & 15);
#pragma unroll
          for (int nf = 0; nf < 8; ++nf)
            atomicAdd(yr + nf * 16, sc * acc[mf][nf][reg]);
        }
      }
    }
  }
}

// ---------------- launch ----------------
extern "C" void kernel_launch(void* const* d_in, const int* in_sizes, int n_in,
                              void* d_out, int out_size, void* d_ws, size_t ws_size,
                              hipStream_t stream) {
  const float* x = (const float*)d_in[0];
  const int* topk_idx = (const int*)d_in[1];
  const float* topk_sc = (const float*)d_in[2];
  const float* Wg = (const float*)d_in[3];
  const float* Wu = (const float*)d_in[4];
  const float* Wd = (const float*)d_in[5];
  float* y = (float*)d_out;

  char* p = (char*)d_ws;
  auto take = [&](size_t b) { char* r = p; p += (b + 255) & ~(size_t)255; return r; };
  int* counts = (int*)take(EE * 4);
  int* cursor = (int*)take(EE * 4);
  int* off = (int*)take((EE + 1) * 4);
  int* rows_token = (int*)take((size_t)NA * 4);
  float* rows_score = (float*)take((size_t)NA * 4);
  __hip_bfloat16* xb = (__hip_bfloat16*)take((size_t)TT * DD * 2);
  __hip_bfloat16* Wgb = (__hip_bfloat16*)take((size_t)EE * DD * HH * 2);
  __hip_bfloat16* Wub = (__hip_bfloat16*)take((size_t)EE * DD * HH * 2);
  __hip_bfloat16* Wdb = (__hip_bfloat16*)take((size_t)EE * DD * HH * 2);
  __hip_bfloat16* hbuf = (__hip_bfloat16*)take((size_t)NA * HH * 2);

  hipMemsetAsync(d_out, 0, (size_t)TT * DD * 4, stream);
  k_init<<<1, 64, 0, stream>>>(counts);
  k_count<<<NA / 256, 256, 0, stream>>>(topk_idx, counts);
  k_scan<<<1, 1, 0, stream>>>(counts, off, cursor);
  k_scatter<<<NA / 256, 256, 0, stream>>>(topk_idx, topk_sc, cursor, rows_token, rows_score);
  k_cvtx<<<TT * DD / 4 / 256, 256, 0, stream>>>(x, xb);
  dim3 tg(HH / 32, DD / 32, EE);
  k_tc<<<tg, dim3(32, 8), 0, stream>>>(Wg, Wgb, DD, HH);
  k_tc<<<tg, dim3(32, 8), 0, stream>>>(Wu, Wub, DD, HH);
  dim3 td(DD / 32, HH / 32, EE);
  k_tc<<<td, dim3(32, 8), 0, stream>>>(Wd, Wdb, HH, DD);
  k_gemm1<<<dim3(HH / 64, 20, EE), 256, 0, stream>>>(xb, Wgb, Wub, rows_token, off, hbuf);
  k_gemm2<<<dim3(DD / 128, 20, EE), 256, 0, stream>>>(hbuf, Wdb, rows_token, rows_score, off, y);
}